// Round 7
// baseline (237.496 us; speedup 1.0000x reference)
//
#include <hip/hip_runtime.h>

#define B_ 32
#define CI 128
#define CO 256
#define K_DIM 1152            // 9*128
#define M_DIM 100352          // 32*56*56
#define BM 256
#define BN 256
#define NSLOT 36              // K_DIM / 32 (BK=32 slots, double-buffered)
#define HPAD 58               // 56 + halo
#define XB_OFF 589824         // byte offset of xb in ws (after wt: 1152*256*2 B)
#define WTBLK 72              // (K_DIM/64)*(CO/64) transpose tiles
#define XPBLK 6728            // (B_*HPAD*HPAD*16)/256 pad blocks
#define GRID_M 392            // M_DIM / BM = 49*8 (divisible by 8 XCDs)

typedef float          floatx4  __attribute__((ext_vector_type(4)));
typedef unsigned short ushortx8 __attribute__((ext_vector_type(8)));
typedef __bf16         bf16x8   __attribute__((ext_vector_type(8)));

typedef __attribute__((address_space(1))) void gas_void;
typedef __attribute__((address_space(3))) void las_void;
#define GLD16(g, l) __builtin_amdgcn_global_load_lds( \
    (gas_void*)(uintptr_t)(g), (las_void*)(l), 16, 0, 0)

__device__ __forceinline__ unsigned short bf16_rne(float f) {
    unsigned u = __builtin_bit_cast(unsigned, f);
    u += 0x7FFFu + ((u >> 16) & 1u);
    return (unsigned short)(u >> 16);
}

// ---- fused prepass: blocks [0,72) transpose w -> wt bf16 [256][1152];
//      blocks [72, 72+6728) pad x -> xb bf16 [32][58][58][128] with zero halo.
__global__ void prepass_kernel(const float* __restrict__ x,
                               const float* __restrict__ w,
                               unsigned short* __restrict__ xb,
                               unsigned short* __restrict__ wt) {
    __shared__ unsigned short tile[64][65];
    if (blockIdx.x < WTBLK) {
        const int kt = (blockIdx.x % 18) * 64, nt = (blockIdx.x / 18) * 64;
        #pragma unroll
        for (int i = 0; i < 16; ++i) {
            int idx = i * 256 + threadIdx.x;
            int kl = idx >> 6, nl = idx & 63;
            tile[kl][nl] = bf16_rne(w[(size_t)(kt + kl) * CO + nt + nl]);
        }
        __syncthreads();
        #pragma unroll
        for (int i = 0; i < 16; ++i) {
            int idx = i * 256 + threadIdx.x;
            int nl = idx >> 6, kl = idx & 63;
            wt[(size_t)(nt + nl) * K_DIM + kt + kl] = tile[kl][nl];
        }
    } else {
        const int t   = (blockIdx.x - WTBLK) * 256 + threadIdx.x;
        const int pix = t >> 4;
        const int cc  = (t & 15) << 3;
        const int b   = pix / (HPAD * HPAD);
        const int rem = pix % (HPAD * HPAD);
        const int hp  = rem / HPAD, wp = rem % HPAD;
        ushortx8 g = {0, 0, 0, 0, 0, 0, 0, 0};
        if (hp >= 1 && hp <= 56 && wp >= 1 && wp <= 56) {
            const float* s = x + ((size_t)((b * 56 + hp - 1) * 56 + (wp - 1))) * CI + cc;
            floatx4 f0 = ((const floatx4*)s)[0];
            floatx4 f1 = ((const floatx4*)s)[1];
            #pragma unroll
            for (int e = 0; e < 4; ++e) { g[e] = bf16_rne(f0[e]); g[e + 4] = bf16_rne(f1[e]); }
        }
        *(ushortx8*)(xb + (size_t)pix * CI + cc) = g;
    }
}

// ---- main: implicit-GEMM conv. Geometry chosen by the LDS-BW roofline:
// per-wave LDS reads = (Mw+Nw)*K*2B vs FLOP = Mw*Nw*K*2, so MfmaUtil cap
// scales with Mw*Nw/(Mw+Nw). 64x64/wave caps ~30-41% (R0/R6/m97, all match);
// 128x64/wave at 256^2 caps ~62% (m201's measured 62.1%).
// => 256x256 block, 8 waves (2Mx4N), 128x64 per wave, acc[8][4].
// Schedule: m97's one-sync double-buffer at BK=32 (same 64 KB LDS as
// single-buffered BK=64 -> 2 blocks/CU, absorbs the 392-block grid tail and
// gives cross-block overlap): { stage(t+1, buf^1); compute(t, buf); sync }.
// Stage latency drains under the 32 MFMAs; no inline asm, no setprio
// (lockstep regime). Rotation chunk swizzle + fragment offsets + stage
// address formulas + C/D epilogue carried over verbatim (verified, 0 bank
// conflicts, absmax 0.0625).
__global__ __launch_bounds__(512, 2)
void conv_gemm_kernel(const unsigned short* __restrict__ xb,
                      const unsigned short* __restrict__ wt,
                      const float* __restrict__ bias,
                      float* __restrict__ out) {
    __shared__ unsigned short As[2][BM * 32];   // [buf][row*32+chunk], 2 x 16 KB
    __shared__ unsigned short Bs[2][BN * 32];   // 2 x 16 KB  (total 64 KB)

    const int tid  = threadIdx.x;
    const int bid  = blockIdx.x;
    const int by   = (bid & 7) * (GRID_M / 8) + (bid >> 3);  // XCD-contiguous m-tiles
    const int wid  = tid >> 6;               // 0..7
    const int lane = tid & 63;
    const int lrow = lane & 15;
    const int quad = lane >> 4;
    const int wm   = (wid & 1) * 128;        // wave rows: 128 of 256
    const int wn   = (wid >> 1) * 64;        // wave cols: 64 of 256

    // staging lane mapping (verified): seg-row = lane>>2, slot = lane&3,
    // fetch global chunk (slot - (rseg>>1)) & 3
    const int rseg = lane >> 2;
    const int cglb = ((lane & 3) - (rseg >> 1)) & 3;

    // global row bases for the two 128-row GLD rounds
    const unsigned short* aga[2];
    const unsigned short* bga[2];
    #pragma unroll
    for (int g = 0; g < 2; ++g) {
        const int m0 = by * BM + g * 128 + wid * 16 + rseg;
        const int b0 = m0 / 3136, r0 = m0 % 3136;
        aga[g] = xb + ((size_t)((b0 * HPAD + r0 / 56) * HPAD + r0 % 56)) * CI + cglb * 8;
        const int n0 = g * 128 + wid * 16 + rseg;
        bga[g] = wt + (size_t)n0 * K_DIM + cglb * 8;
    }
    const int wbase = wid * 512;             // (wid*16)*32 elements within a plane

    // fragment read offsets within a [256][32] plane (verified)
    const int swz = ((quad + (lrow >> 1)) & 3) * 8;
    int arow[8], brow[4];
    #pragma unroll
    for (int i = 0; i < 8; ++i) arow[i] = (wm + i * 16 + lrow) * 32 + swz;
    #pragma unroll
    for (int i = 0; i < 4; ++i) brow[i] = (wn + i * 16 + lrow) * 32 + swz;

    floatx4 acc[8][4] = {};

    // stage K-slot u (K-offset u*32) into buffer P: 2+2 GLD16/thread
    auto stageA = [&](int u, int P) {
        const int p    = u >> 2;             // patch 0..8
        const int aoff = (p / 3 * HPAD + p % 3) * CI + (u & 3) * 32;
        GLD16(aga[0] + aoff, &As[P][wbase]);
        GLD16(aga[1] + aoff, &As[P][4096 + wbase]);
    };
    auto stageB = [&](int u, int P) {
        const int boff = u * 32;
        GLD16(bga[0] + boff, &Bs[P][wbase]);
        GLD16(bga[1] + boff, &Bs[P][4096 + wbase]);
    };

    // one K-slot of compute: 12 ds_read_b128 (4 B + 8 A), 32 MFMA
    auto compute = [&](int P) {
        ushortx8 bfr[4], afr[8];
        #pragma unroll
        for (int ni = 0; ni < 4; ++ni) bfr[ni] = *(const ushortx8*)&Bs[P][brow[ni]];
        #pragma unroll
        for (int i = 0; i < 8; ++i) afr[i] = *(const ushortx8*)&As[P][arow[i]];
        #pragma unroll
        for (int i = 0; i < 8; ++i)
            #pragma unroll
            for (int ni = 0; ni < 4; ++ni)
                acc[i][ni] = __builtin_amdgcn_mfma_f32_16x16x32_bf16(
                    __builtin_bit_cast(bf16x8, afr[i]),
                    __builtin_bit_cast(bf16x8, bfr[ni]),
                    acc[i][ni], 0, 0, 0);
    };

    stageA(0, 0); stageB(0, 0);
    __syncthreads();
    #pragma unroll 1
    for (int u = 0; u < NSLOT - 1; ++u) {
        const int b = u & 1;
        stageA(u + 1, b ^ 1);                // issue next slot's 4 GLD16 first
        stageB(u + 1, b ^ 1);                //   -> latency drains under MFMAs
        compute(b);
        __syncthreads();                     // publishes u+1, protects WAR on b
    }
    compute(1);                              // slot 35 resides in buf 1

    // epilogue: bias + store (C/D: col=lane&15, row=quad*4+r)
    float bv[4];
    #pragma unroll
    for (int ni = 0; ni < 4; ++ni)
        bv[ni] = bias[wn + ni * 16 + lrow];

    #pragma unroll
    for (int mi = 0; mi < 8; ++mi) {
        #pragma unroll
        for (int r = 0; r < 4; ++r) {
            const int row = by * BM + wm + mi * 16 + quad * 4 + r;
            float* o = out + (size_t)row * CO + wn + lrow;
            #pragma unroll
            for (int ni = 0; ni < 4; ++ni)
                o[ni * 16] = acc[mi][ni][r] + bv[ni];
        }
    }
}

extern "C" void kernel_launch(void* const* d_in, const int* in_sizes, int n_in,
                              void* d_out, int out_size, void* d_ws, size_t ws_size,
                              hipStream_t stream) {
    (void)in_sizes; (void)n_in; (void)out_size; (void)ws_size;
    const float* x    = (const float*)d_in[0];
    const float* w    = (const float*)d_in[1];
    const float* bias = (const float*)d_in[2];
    float* out = (float*)d_out;

    unsigned short* wt = (unsigned short*)d_ws;                     // bf16 [256][1152]
    unsigned short* xb = (unsigned short*)((char*)d_ws + XB_OFF);   // bf16 [32][58][58][128]

    prepass_kernel<<<dim3(WTBLK + XPBLK), dim3(256), 0, stream>>>(x, w, xb, wt);
    conv_gemm_kernel<<<dim3(GRID_M), dim3(512), 0, stream>>>(xb, wt, bias, out);
}

// Round 8
// 209.502 us; speedup vs baseline: 1.1336x; 1.1336x over previous
//
#include <hip/hip_runtime.h>

#define B_ 32
#define CI 128
#define CO 256
#define K_DIM 1152            // 9*128
#define M_DIM 100352          // 32*56*56
#define BM 128
#define BN 256
#define KT 18                 // K-tiles of 64 (2 sub-plane slots of 32)
#define HPAD 58               // 56 + halo
#define XB_OFF 589824         // byte offset of xb in ws (after wt: 1152*256*2 B)
#define WTBLK 72              // (K_DIM/64)*(CO/64) transpose tiles
#define XPBLK 6728            // (B_*HPAD*HPAD*16)/256 pad blocks
#define GRID_M 784            // M_DIM / BM = 98*8 (divisible by 8 XCDs)

typedef float          floatx4  __attribute__((ext_vector_type(4)));
typedef unsigned short ushortx8 __attribute__((ext_vector_type(8)));
typedef __bf16         bf16x8   __attribute__((ext_vector_type(8)));

typedef __attribute__((address_space(1))) void gas_void;
typedef __attribute__((address_space(3))) void las_void;
#define GLD16(g, l) __builtin_amdgcn_global_load_lds( \
    (gas_void*)(uintptr_t)(g), (las_void*)(l), 16, 0, 0)

__device__ __forceinline__ unsigned short bf16_rne(float f) {
    unsigned u = __builtin_bit_cast(unsigned, f);
    u += 0x7FFFu + ((u >> 16) & 1u);
    return (unsigned short)(u >> 16);
}

// ---- fused prepass: blocks [0,72) transpose w -> wt bf16 [256][1152];
//      blocks [72, 72+6728) pad x -> xb bf16 [32][58][58][128] with zero halo.
__global__ void prepass_kernel(const float* __restrict__ x,
                               const float* __restrict__ w,
                               unsigned short* __restrict__ xb,
                               unsigned short* __restrict__ wt) {
    __shared__ unsigned short tile[64][65];
    if (blockIdx.x < WTBLK) {
        const int kt = (blockIdx.x % 18) * 64, nt = (blockIdx.x / 18) * 64;
        #pragma unroll
        for (int i = 0; i < 16; ++i) {
            int idx = i * 256 + threadIdx.x;
            int kl = idx >> 6, nl = idx & 63;
            tile[kl][nl] = bf16_rne(w[(size_t)(kt + kl) * CO + nt + nl]);
        }
        __syncthreads();
        #pragma unroll
        for (int i = 0; i < 16; ++i) {
            int idx = i * 256 + threadIdx.x;
            int nl = idx >> 6, kl = idx & 63;
            wt[(size_t)(nt + nl) * K_DIM + kt + kl] = tile[kl][nl];
        }
    } else {
        const int t   = (blockIdx.x - WTBLK) * 256 + threadIdx.x;
        const int pix = t >> 4;
        const int cc  = (t & 15) << 3;
        const int b   = pix / (HPAD * HPAD);
        const int rem = pix % (HPAD * HPAD);
        const int hp  = rem / HPAD, wp = rem % HPAD;
        ushortx8 g = {0, 0, 0, 0, 0, 0, 0, 0};
        if (hp >= 1 && hp <= 56 && wp >= 1 && wp <= 56) {
            const float* s = x + ((size_t)((b * 56 + hp - 1) * 56 + (wp - 1))) * CI + cc;
            floatx4 f0 = ((const floatx4*)s)[0];
            floatx4 f1 = ((const floatx4*)s)[1];
            #pragma unroll
            for (int e = 0; e < 4; ++e) { g[e] = bf16_rne(f0[e]); g[e + 4] = bf16_rne(f1[e]); }
        }
        *(ushortx8*)(xb + (size_t)pix * CI + cc) = g;
    }
}

// ---- main: implicit-GEMM conv, R6's proven schedule with improved geometry.
// Session data: sync-per-310cyc-MFMA structures hit 26.5-29.5% (R0/R2/R6);
// finer cadence or deeper pipelines regress (R5 22.7%, R7 20.0% = the m196
// "coarse split hurts" pattern). So keep R6's cadence verbatim and move the
// two free levers:
//  * wave geometry: 64x128/wave (4 waves, 2Mx2N) -> FLOP per ds_read_b128 =
//    2.67 vs R6's 2.0 (+33% on the LDS-read axis).
//  * grid fit: BM=128,BN=256 single-buffered BK=64 = 48 KB LDS -> 3 blk/CU,
//    capacity 768 vs grid 784 -> 1.02 rounds (R6: 1.53). Full-N per block
//    restores B reuse (FETCH ~18 MB vs R6's 47 MB).
// Cross-block TLP (3 blocks/CU, m114 mechanism) does the latency hiding; no
// dbuf, no manual vmcnt, no setprio. Rotation chunk swizzle + fragment
// offsets + patch address formulas + C/D epilogue carried over verbatim
// (verified, 0 bank conflicts, absmax 0.0625).
__global__ __launch_bounds__(256, 2)
void conv_gemm_kernel(const unsigned short* __restrict__ xb,
                      const unsigned short* __restrict__ wt,
                      const float* __restrict__ bias,
                      float* __restrict__ out) {
    __shared__ unsigned short As[2][BM * 32];   // [kk][row*32+chunk], 2 x 8 KB
    __shared__ unsigned short Bs[2][BN * 32];   // [kk][row*32+chunk], 2 x 16 KB

    const int tid  = threadIdx.x;
    const int bid  = blockIdx.x;
    const int by   = (bid & 7) * (GRID_M / 8) + (bid >> 3);  // XCD-contiguous m-tiles
    const int wid  = tid >> 6;               // 0..3
    const int lane = tid & 63;
    const int lrow = lane & 15;
    const int quad = lane >> 4;
    const int wm   = (wid & 1) * 64;         // wave rows: 64 of 128
    const int wn   = (wid >> 1) * 128;       // wave cols: 128 of 256

    // staging lane mapping (verified): seg-row = lane>>2, slot = lane&3,
    // fetch global chunk (slot - (rseg>>1)) & 3
    const int rseg = lane >> 2;
    const int cglb = ((lane & 3) - (rseg >> 1)) & 3;

    // global row bases: A has 2 rounds of 64 rows, B has 4 rounds of 64 rows
    const unsigned short* aga[2];
    const unsigned short* bga[4];
    #pragma unroll
    for (int g = 0; g < 2; ++g) {
        const int m0 = by * BM + g * 64 + wid * 16 + rseg;
        const int b0 = m0 / 3136, r0 = m0 % 3136;
        aga[g] = xb + ((size_t)((b0 * HPAD + r0 / 56) * HPAD + r0 % 56)) * CI + cglb * 8;
    }
    #pragma unroll
    for (int g = 0; g < 4; ++g) {
        const int n0 = g * 64 + wid * 16 + rseg;
        bga[g] = wt + (size_t)n0 * K_DIM + cglb * 8;
    }
    const int wbase = wid * 512;             // (wid*16)*32 elements

    // fragment read offsets within a [rows][32] sub-plane (verified)
    const int swz = ((quad + (lrow >> 1)) & 3) * 8;
    int arow[4], brow[8];
    #pragma unroll
    for (int i = 0; i < 4; ++i) arow[i] = (wm + i * 16 + lrow) * 32 + swz;
    #pragma unroll
    for (int i = 0; i < 8; ++i) brow[i] = (wn + i * 16 + lrow) * 32 + swz;

    floatx4 acc[4][8] = {};

    // stage K-slot u (K-offset u*32) into sub-plane kk = u&1
    auto stageA = [&](int u) {               // 2 GLD16 (2 rounds of 64 rows)
        const int p    = u >> 2;             // patch 0..8
        const int aoff = (p / 3 * HPAD + p % 3) * CI + (u & 3) * 32;
        GLD16(aga[0] + aoff, &As[u & 1][wbase]);
        GLD16(aga[1] + aoff, &As[u & 1][2048 + wbase]);
    };
    auto stageB = [&](int u) {               // 4 GLD16 (4 rounds of 64 rows)
        const int boff = u * 32;
        GLD16(bga[0] + boff, &Bs[u & 1][wbase]);
        GLD16(bga[1] + boff, &Bs[u & 1][2048 + wbase]);
        GLD16(bga[2] + boff, &Bs[u & 1][4096 + wbase]);
        GLD16(bga[3] + boff, &Bs[u & 1][6144 + wbase]);
    };

    // one K-slot of compute: 12 ds_read_b128 (4 A + 8 B), 32 MFMA
    auto compute = [&](int kk) {
        ushortx8 afr[4], bfr[8];
        #pragma unroll
        for (int i = 0; i < 4; ++i) afr[i] = *(const ushortx8*)&As[kk][arow[i]];
        #pragma unroll
        for (int ni = 0; ni < 8; ++ni) bfr[ni] = *(const ushortx8*)&Bs[kk][brow[ni]];
        #pragma unroll
        for (int i = 0; i < 4; ++i)
            #pragma unroll
            for (int ni = 0; ni < 8; ++ni)
                acc[i][ni] = __builtin_amdgcn_mfma_f32_16x16x32_bf16(
                    __builtin_bit_cast(bf16x8, afr[i]),
                    __builtin_bit_cast(bf16x8, bfr[ni]),
                    acc[i][ni], 0, 0, 0);
    };

    #pragma unroll 1
    for (int t = 0; t < KT; ++t) {
        const int u = t * 2;
        stageA(u);     stageB(u);            // 12 GLD16/thread total
        stageA(u + 1); stageB(u + 1);
        __syncthreads();                     // publishes tile t (drains vmcnt)
        compute(0);
        compute(1);
        __syncthreads();                     // reads done before next stage
    }

    // epilogue: bias + store (C/D: col=lane&15, row=quad*4+r)
    float bv[8];
    #pragma unroll
    for (int ni = 0; ni < 8; ++ni)
        bv[ni] = bias[wn + ni * 16 + lrow];

    #pragma unroll
    for (int mi = 0; mi < 4; ++mi) {
        #pragma unroll
        for (int r = 0; r < 4; ++r) {
            const int row = by * BM + wm + mi * 16 + quad * 4 + r;
            float* o = out + (size_t)row * CO + wn + lrow;
            #pragma unroll
            for (int ni = 0; ni < 8; ++ni)
                o[ni * 16] = acc[mi][ni][r] + bv[ni];
        }
    }
}

extern "C" void kernel_launch(void* const* d_in, const int* in_sizes, int n_in,
                              void* d_out, int out_size, void* d_ws, size_t ws_size,
                              hipStream_t stream) {
    (void)in_sizes; (void)n_in; (void)out_size; (void)ws_size;
    const float* x    = (const float*)d_in[0];
    const float* w    = (const float*)d_in[1];
    const float* bias = (const float*)d_in[2];
    float* out = (float*)d_out;

    unsigned short* wt = (unsigned short*)d_ws;                     // bf16 [256][1152]
    unsigned short* xb = (unsigned short*)((char*)d_ws + XB_OFF);   // bf16 [32][58][58][128]

    prepass_kernel<<<dim3(WTBLK + XPBLK), dim3(256), 0, stream>>>(x, w, xb, wt);
    conv_gemm_kernel<<<dim3(GRID_M), dim3(256), 0, stream>>>(xb, wt, bias, out);
}